// Round 7
// baseline (248.668 us; speedup 1.0000x reference)
//
#include <hip/hip_runtime.h>
#include <hip/hip_bf16.h>
#include <stdint.h>

// Problem constants (T=128, B=64, H=1024)
#define TT 128
#define BB 64
#define HH 1024
#define MM (TT * BB)          // 8192 rows of the two GEMMs
#define NLANE (BB * HH)       // 65536 scan lanes
#define DELTA 1.0e-4          // flag band; bf16 3-pass error <= ~1e-5 max (10x margin)
#define CAPL 32768            // hraw capacity in lanes (overlay on xp region)
#define F16_ONE 0x3C00        // _Float16 1.0

typedef __attribute__((ext_vector_type(8))) short bf16x8;
typedef __attribute__((ext_vector_type(8))) _Float16 f16x8;
typedef __attribute__((ext_vector_type(4))) float f32x4;

// async global->LDS, 16 B per lane; LDS dest = wave-uniform base + lane*16
#define GLOAD16(g, l)                                                        \
    __builtin_amdgcn_global_load_lds(                                        \
        (const __attribute__((address_space(1))) unsigned int*)(g),          \
        (__attribute__((address_space(3))) unsigned int*)(l), 16, 0, 0)

static __device__ __forceinline__ unsigned short bf16_bits(float f) {
    __hip_bfloat16 b = __float2bfloat16(f);
    return *reinterpret_cast<unsigned short*>(&b);
}
static __device__ __forceinline__ unsigned short f16_bits(float f) {
    _Float16 h = (_Float16)f;
    return *reinterpret_cast<unsigned short*>(&h);
}

// ---------------------------------------------------------------------------
// Fused prep (one dispatch):
//   blocks [0,8192)      : split X  -> bf16 Xhi, Xlo (lo unscaled: bf16 has
//                          f32's exponent range, no subnormal hazard)
//   blocks [8192,9216)   : split W1 -> bf16 W1hi, W1lo
//   blocks [9216,10240)  : cast  W2 -> f16
//   block 0 thread 0     : cnt = 0
// ---------------------------------------------------------------------------
__global__ __launch_bounds__(256) void prep_fused(const float* __restrict__ x,
                                                  const float* __restrict__ W1,
                                                  const float* __restrict__ W2,
                                                  unsigned short* __restrict__ Xhi,
                                                  unsigned short* __restrict__ Xlo,
                                                  unsigned short* __restrict__ W1hi,
                                                  unsigned short* __restrict__ W1lo,
                                                  unsigned short* __restrict__ w2h,
                                                  int* __restrict__ cnt) {
    const int bid = blockIdx.x;
    if (bid == 0 && threadIdx.x == 0) *cnt = 0;

    const float* src;
    unsigned short *hi, *lo;
    int i;
    bool split;
    if (bid < 8192) {
        i = bid * 256 + threadIdx.x;
        src = x; hi = Xhi; lo = Xlo; split = true;
    } else if (bid < 9216) {
        i = (bid - 8192) * 256 + threadIdx.x;
        src = W1; hi = W1hi; lo = W1lo; split = true;
    } else {
        i = (bid - 9216) * 256 + threadIdx.x;
        src = W2; hi = w2h; lo = nullptr; split = false;
    }

    float4 v4 = reinterpret_cast<const float4*>(src)[i];
    float v[4] = {v4.x, v4.y, v4.z, v4.w};
    unsigned short hb[4], lb[4];
#pragma unroll
    for (int c = 0; c < 4; c++) {
        if (split) {
            hb[c] = bf16_bits(v[c]);
            __hip_bfloat16 hh = *reinterpret_cast<__hip_bfloat16*>(&hb[c]);
            lb[c] = bf16_bits(v[c] - __bfloat162float(hh));
        } else {
            hb[c] = f16_bits(v[c]);
        }
    }
    reinterpret_cast<ushort4*>(hi)[i] = make_ushort4(hb[0], hb[1], hb[2], hb[3]);
    if (split)
        reinterpret_cast<ushort4*>(lo)[i] = make_ushort4(lb[0], lb[1], lb[2], lb[3]);
}

// ---------------------------------------------------------------------------
// GEMM1 via 3-pass split-bf16 MFMA, SINGLE accumulator (no fold, no scaling):
//   acc += aH·bH + aH·bL + aL·bH       (dropped lo·lo ~1e-6 rms)
// 128x128 tile, BK=32, 4 waves 2x2; XOR-swizzled LDS (conflicts=0, round 5);
// global_load_lds staging.  Round-4 structure (61 us) + swizzle, no fmac tax.
// ---------------------------------------------------------------------------
__global__ __launch_bounds__(256) void gemm1_mfma(const unsigned short* __restrict__ Ah,
                                                  const unsigned short* __restrict__ Al,
                                                  const unsigned short* __restrict__ Bh,
                                                  const unsigned short* __restrict__ Bl,
                                                  float* __restrict__ C) {
    __shared__ short AsH[128 * 32];
    __shared__ short AsL[128 * 32];
    __shared__ short BsH[128 * 32];
    __shared__ short BsL[128 * 32];

    const int tid = threadIdx.x;
    const int lane = tid & 63;
    const int wave = tid >> 6;
    const int m0 = blockIdx.x * 128;
    const int n0 = blockIdx.y * 128;
    const int wm = (wave >> 1) * 64;
    const int wn = (wave & 1) * 64;

    const int rsel = lane & 15;
    const int part = lane >> 4;

    int adrA[4], adrB[4];
#pragma unroll
    for (int i = 0; i < 4; i++) {
        const int ra = wm + i * 16 + rsel;
        const int rb = wn + i * 16 + rsel;
        adrA[i] = ra * 32 + (part ^ ((ra >> 1) & 3)) * 8;
        adrB[i] = rb * 32 + (part ^ ((rb >> 1) & 3)) * 8;
    }

    f32x4 acc[4][4] = {};

    for (int k0 = 0; k0 < HH; k0 += 32) {
#pragma unroll
        for (int p = 0; p < 2; p++) {
            const int c = tid + p * 256;
            const int cb = wave * 64 + p * 256;
            const int row = c >> 2;
            const int pslot = c & 3;
            const int pdata = pslot ^ ((row >> 1) & 3);
            const size_t goA = (size_t)(m0 + row) * HH + k0 + pdata * 8;
            const size_t goB = (size_t)(n0 + row) * HH + k0 + pdata * 8;
            GLOAD16(&Ah[goA], &AsH[cb * 8]);
            GLOAD16(&Al[goA], &AsL[cb * 8]);
            GLOAD16(&Bh[goB], &BsH[cb * 8]);
            GLOAD16(&Bl[goB], &BsL[cb * 8]);
        }
        __syncthreads();

        bf16x8 aH[4], aL[4], bH[4], bL[4];
#pragma unroll
        for (int mi = 0; mi < 4; mi++) {
            aH[mi] = *reinterpret_cast<bf16x8*>(&AsH[adrA[mi]]);
            aL[mi] = *reinterpret_cast<bf16x8*>(&AsL[adrA[mi]]);
        }
#pragma unroll
        for (int ni = 0; ni < 4; ni++) {
            bH[ni] = *reinterpret_cast<bf16x8*>(&BsH[adrB[ni]]);
            bL[ni] = *reinterpret_cast<bf16x8*>(&BsL[adrB[ni]]);
        }

#pragma unroll
        for (int mi = 0; mi < 4; mi++)
#pragma unroll
            for (int ni = 0; ni < 4; ni++) {
                acc[mi][ni] = __builtin_amdgcn_mfma_f32_16x16x32_bf16(aH[mi], bH[ni], acc[mi][ni], 0, 0, 0);
                acc[mi][ni] = __builtin_amdgcn_mfma_f32_16x16x32_bf16(aH[mi], bL[ni], acc[mi][ni], 0, 0, 0);
                acc[mi][ni] = __builtin_amdgcn_mfma_f32_16x16x32_bf16(aL[mi], bH[ni], acc[mi][ni], 0, 0, 0);
            }

        __syncthreads();
    }

    const int col = lane & 15;
    const int quad = lane >> 4;
#pragma unroll
    for (int mi = 0; mi < 4; mi++)
#pragma unroll
        for (int ni = 0; ni < 4; ni++) {
            const int m = m0 + wm + mi * 16 + quad * 4;
            const int n = n0 + wn + ni * 16 + col;
            float* dst = &C[(size_t)m * HH + n];
#pragma unroll
            for (int r = 0; r < 4; r++)
                dst[(size_t)r * HH] = acc[mi][ni][r];
        }
}

// ---------------------------------------------------------------------------
// LIF scan (f64 on fp32 x_proj) + flagging, with 4-deep load prefetch:
// addresses are v-independent, so loads overlap the serial f64 chain.
// ---------------------------------------------------------------------------
__global__ __launch_bounds__(256) void lif_scan_flag(const float* __restrict__ xp,
                                                     unsigned short* __restrict__ sp,
                                                     int* __restrict__ count,
                                                     int* __restrict__ list) {
    const int idx = blockIdx.x * 256 + threadIdx.x;
    const float* p = xp + idx;
    float buf[4];
#pragma unroll
    for (int i = 0; i < 4; i++) buf[i] = p[(size_t)i * NLANE];

    double v = 0.0;
    bool flg = false;
#pragma unroll 4
    for (int t = 0; t < TT; t++) {
        const float xf = buf[t & 3];
        if (t + 4 < TT) buf[t & 3] = p[(size_t)(t + 4) * NLANE];
        const double x = (double)xf;
        const double h = v + (x - v) * 0.5;
        const bool s = (h >= 1.0);
        flg |= (fabs(h - 1.0) < DELTA);
        v = s ? 0.0 : h;
        sp[(size_t)t * NLANE + idx] = s ? (unsigned short)F16_ONE : (unsigned short)0;
    }
    if (flg) {
        const int i = atomicAdd(count, 1);
        list[i] = idx;
    }
}

// ---------------------------------------------------------------------------
// Task-parallel exact f64 dots for flagged lanes: one WAVE per (li, t) task
// (round-4 structure: no serial-depth pathology, coalesced float4 loads).
// ---------------------------------------------------------------------------
__global__ __launch_bounds__(256) void recompute_dots(const float* __restrict__ X,
                                                      const float* __restrict__ W1,
                                                      const int* __restrict__ count,
                                                      const int* __restrict__ list,
                                                      double* __restrict__ hraw) {
    const int cnt = *count;
    const int lim = (cnt < CAPL ? cnt : CAPL);
    const long ntask = (long)lim * TT;
    const int ln = threadIdx.x & 63;
    const long wid = (long)blockIdx.x * 4 + (threadIdx.x >> 6);
    const long nwaves = (long)gridDim.x * 4;

    for (long task = wid; task < ntask; task += nwaves) {
        const int li = (int)(task >> 7);
        const int t = (int)(task & (TT - 1));
        const int lane = list[li];
        const int b = lane >> 10;
        const int h = lane & (HH - 1);
        const float4* x4 = reinterpret_cast<const float4*>(X + (size_t)(t * BB + b) * HH);
        const float4* w4 = reinterpret_cast<const float4*>(W1 + (size_t)h * HH);

        double s0 = 0.0, s1 = 0.0, s2 = 0.0, s3 = 0.0;
#pragma unroll
        for (int i = 0; i < 4; i++) {
            const float4 xa = x4[ln + i * 64];
            const float4 wa = w4[ln + i * 64];
            s0 = fma((double)xa.x, (double)wa.x, s0);
            s1 = fma((double)xa.y, (double)wa.y, s1);
            s2 = fma((double)xa.z, (double)wa.z, s2);
            s3 = fma((double)xa.w, (double)wa.w, s3);
        }
        double s = (s0 + s1) + (s2 + s3);
#pragma unroll
        for (int off = 32; off >= 1; off >>= 1)
            s += __shfl_down(s, off);
        if (ln == 0) hraw[task] = s;
    }
}

// ---------------------------------------------------------------------------
// Exact f64 rescan of flagged lanes from hraw; overwrite their spikes.
// Serial-dot fallback for li >= CAPL keeps correctness capacity-independent.
// ---------------------------------------------------------------------------
__global__ __launch_bounds__(256) void rescan_lanes(const float* __restrict__ X,
                                                    const float* __restrict__ W1,
                                                    const int* __restrict__ count,
                                                    const int* __restrict__ list,
                                                    const double* __restrict__ hraw,
                                                    unsigned short* __restrict__ sp) {
    const int li = blockIdx.x * 256 + threadIdx.x;
    const int cnt = *count;
    if (li >= cnt) return;
    const int lane = list[li];

    double v = 0.0;
    if (li < CAPL) {
        const double* hb = hraw + (size_t)li * TT;
        for (int t = 0; t < TT; t++) {
            const double h = v + (hb[t] - v) * 0.5;
            const bool s = (h >= 1.0);
            v = s ? 0.0 : h;
            sp[(size_t)t * NLANE + lane] = s ? (unsigned short)F16_ONE : (unsigned short)0;
        }
    } else {
        const int b = lane >> 10;
        const int h = lane & (HH - 1);
        const float* wrow = W1 + (size_t)h * HH;
        for (int t = 0; t < TT; t++) {
            const float* xrow = X + (size_t)(t * BB + b) * HH;
            double d = 0.0;
            for (int k = 0; k < HH; k++)
                d = fma((double)xrow[k], (double)wrow[k], d);
            const double hh = v + (d - v) * 0.5;
            const bool s = (hh >= 1.0);
            v = s ? 0.0 : hh;
            sp[(size_t)t * NLANE + lane] = s ? (unsigned short)F16_ONE : (unsigned short)0;
        }
    }
}

// ---------------------------------------------------------------------------
// GEMM2: out = S · W2^T in f16 MFMA, BK=64 (32 MFMA per barrier pair),
// XOR-swizzled LDS: chunk (row, part 0..7) stored at slot part^(row&7).
// ---------------------------------------------------------------------------
__global__ __launch_bounds__(256) void gemm2_mfma(const unsigned short* __restrict__ S,
                                                  const unsigned short* __restrict__ W,
                                                  float* __restrict__ O) {
    __shared__ short As[128 * 64];   // 16 KB
    __shared__ short Bs[128 * 64];   // 16 KB

    const int tid = threadIdx.x;
    const int lane = tid & 63;
    const int wave = tid >> 6;
    const int m0 = blockIdx.x * 128;
    const int n0 = blockIdx.y * 128;
    const int wm = (wave >> 1) * 64;
    const int wn = (wave & 1) * 64;

    const int rsel = lane & 15;
    const int qpart = lane >> 4;     // 8-elem k-section within a 32-wide half

    // swizzled fragment addresses for k-half h: part = h*4 + qpart
    int adrA[4][2], adrB[4][2];
#pragma unroll
    for (int i = 0; i < 4; i++) {
        const int ra = wm + i * 16 + rsel;
        const int rb = wn + i * 16 + rsel;
#pragma unroll
        for (int h = 0; h < 2; h++) {
            const int pa = h * 4 + qpart;
            adrA[i][h] = ra * 64 + ((pa ^ (ra & 7)) * 8);
            adrB[i][h] = rb * 64 + ((pa ^ (rb & 7)) * 8);
        }
    }

    f32x4 acc[4][4] = {};

    for (int k0 = 0; k0 < HH; k0 += 64) {
#pragma unroll
        for (int p = 0; p < 4; p++) {
            const int c = tid + p * 256;          // chunk 0..1023 (16 B each)
            const int cb = wave * 64 + p * 256;   // wave-uniform base
            const int row = c >> 3;               // 8 chunks per row
            const int pslot = c & 7;
            const int pdata = pslot ^ (row & 7);
            GLOAD16(&S[(size_t)(m0 + row) * HH + k0 + pdata * 8], &As[cb * 8]);
            GLOAD16(&W[(size_t)(n0 + row) * HH + k0 + pdata * 8], &Bs[cb * 8]);
        }
        __syncthreads();

#pragma unroll
        for (int h = 0; h < 2; h++) {
            f16x8 a[4], b[4];
#pragma unroll
            for (int mi = 0; mi < 4; mi++)
                a[mi] = *reinterpret_cast<f16x8*>(&As[adrA[mi][h]]);
#pragma unroll
            for (int ni = 0; ni < 4; ni++)
                b[ni] = *reinterpret_cast<f16x8*>(&Bs[adrB[ni][h]]);

#pragma unroll
            for (int mi = 0; mi < 4; mi++)
#pragma unroll
                for (int ni = 0; ni < 4; ni++)
                    acc[mi][ni] = __builtin_amdgcn_mfma_f32_16x16x32_f16(
                        a[mi], b[ni], acc[mi][ni], 0, 0, 0);
        }

        __syncthreads();
    }

    const int col = lane & 15;
    const int quad = lane >> 4;
#pragma unroll
    for (int mi = 0; mi < 4; mi++)
#pragma unroll
        for (int ni = 0; ni < 4; ni++) {
            const int m = m0 + wm + mi * 16 + quad * 4;
            const int n = n0 + wn + ni * 16 + col;
            float* dst = &O[(size_t)m * HH + n];
#pragma unroll
            for (int r = 0; r < 4; r++)
                dst[(size_t)r * HH] = acc[mi][ni][r];
        }
}

// ---------------------------------------------------------------------------
// Launch (6 dispatches)
// ---------------------------------------------------------------------------
extern "C" void kernel_launch(void* const* d_in, const int* in_sizes, int n_in,
                              void* d_out, int out_size, void* d_ws, size_t ws_size,
                              hipStream_t stream) {
    const float* x  = (const float*)d_in[0];
    const float* W1 = (const float*)d_in[1];
    const float* W2 = (const float*)d_in[2];
    float* out = (float*)d_out;

    char* ws = (char*)d_ws;
    const size_t szX = (size_t)MM * HH;
    const size_t szW = (size_t)HH * HH;

    unsigned short* Xhi  = (unsigned short*)ws;                       // 16.78 MB
    unsigned short* Xlo  = Xhi + szX;                                 // 16.78 MB
    unsigned short* W1hi = Xlo + szX;                                 //  2 MB
    unsigned short* W1lo = W1hi + szW;                                //  2 MB
    unsigned short* w2h  = W1lo + szW;                                //  2 MB
    int*            list = (int*)(w2h + szW);                         // 256 KB
    int*            cnt  = list + NLANE;                              // 4 B
    float*          xp   = (float*)(((uintptr_t)(cnt + 64) + 255) & ~(uintptr_t)255); // 33.5 MB
    unsigned short* sp   = Xhi;          // overlay: spikes reuse Xhi after gemm1
    double*         hraw = (double*)xp;  // overlay: xp dead after lif_scan_flag

    prep_fused<<<10240, 256, 0, stream>>>(x, W1, W2, Xhi, Xlo, W1hi, W1lo, w2h, cnt);

    dim3 g1(MM / 128, HH / 128);
    gemm1_mfma<<<g1, 256, 0, stream>>>(Xhi, Xlo, W1hi, W1lo, xp);

    lif_scan_flag<<<NLANE / 256, 256, 0, stream>>>(xp, sp, cnt, list);

    recompute_dots<<<2048, 256, 0, stream>>>(x, W1, cnt, list, hraw);
    rescan_lanes<<<NLANE / 256, 256, 0, stream>>>(x, W1, cnt, list, hraw, sp);

    dim3 g2(MM / 128, HH / 128);
    gemm2_mfma<<<g2, 256, 0, stream>>>(sp, w2h, out);
}

// Round 8
// 233.850 us; speedup vs baseline: 1.0634x; 1.0634x over previous
//
#include <hip/hip_runtime.h>
#include <hip/hip_bf16.h>
#include <stdint.h>

// Problem constants (T=128, B=64, H=1024)
#define TT 128
#define BB 64
#define HH 1024
#define MM (TT * BB)          // 8192 rows of the two GEMMs
#define NLANE (BB * HH)       // 65536 scan lanes
#define DELTA 1.0e-4          // flag band; bf16 3-pass error <= ~1e-5 max (10x margin)
#define CAPL 32768            // hraw capacity in lanes (overlay on xp region)
#define F16_ONE 0x3C00        // _Float16 1.0

typedef __attribute__((ext_vector_type(8))) short bf16x8;
typedef __attribute__((ext_vector_type(8))) _Float16 f16x8;
typedef __attribute__((ext_vector_type(4))) float f32x4;

// async global->LDS, 16 B per lane; LDS dest = wave-uniform base + lane*16
#define GLOAD16(g, l)                                                        \
    __builtin_amdgcn_global_load_lds(                                        \
        (const __attribute__((address_space(1))) unsigned int*)(g),          \
        (__attribute__((address_space(3))) unsigned int*)(l), 16, 0, 0)

static __device__ __forceinline__ unsigned short bf16_bits(float f) {
    __hip_bfloat16 b = __float2bfloat16(f);
    return *reinterpret_cast<unsigned short*>(&b);
}
static __device__ __forceinline__ unsigned short f16_bits(float f) {
    _Float16 h = (_Float16)f;
    return *reinterpret_cast<unsigned short*>(&h);
}

// ---------------------------------------------------------------------------
// Fused prep (one dispatch) — R6 version (known-good):
//   blocks [0,8192)      : split X  -> bf16 Xhi, Xlo
//   blocks [8192,9216)   : split W1 -> bf16 W1hi, W1lo
//   blocks [9216,10240)  : cast  W2 -> f16
//   block 0 thread 0     : cnt = 0
// ---------------------------------------------------------------------------
__global__ __launch_bounds__(256) void prep_fused(const float* __restrict__ x,
                                                  const float* __restrict__ W1,
                                                  const float* __restrict__ W2,
                                                  unsigned short* __restrict__ Xhi,
                                                  unsigned short* __restrict__ Xlo,
                                                  unsigned short* __restrict__ W1hi,
                                                  unsigned short* __restrict__ W1lo,
                                                  unsigned short* __restrict__ w2h,
                                                  int* __restrict__ cnt) {
    const int bid = blockIdx.x;
    if (bid == 0 && threadIdx.x == 0) *cnt = 0;

    const float* src;
    unsigned short *hi, *lo;
    int i;
    bool split;
    if (bid < 8192) {
        i = bid * 256 + threadIdx.x;
        src = x; hi = Xhi; lo = Xlo; split = true;
    } else if (bid < 9216) {
        i = (bid - 8192) * 256 + threadIdx.x;
        src = W1; hi = W1hi; lo = W1lo; split = true;
    } else {
        i = (bid - 9216) * 256 + threadIdx.x;
        src = W2; hi = w2h; lo = nullptr; split = false;
    }

    float4 v4 = reinterpret_cast<const float4*>(src)[i];
    float v[4] = {v4.x, v4.y, v4.z, v4.w};
    unsigned short hb[4], lb[4];
#pragma unroll
    for (int c = 0; c < 4; c++) {
        if (split) {
            hb[c] = bf16_bits(v[c]);
            __hip_bfloat16 hh = *reinterpret_cast<__hip_bfloat16*>(&hb[c]);
            lb[c] = bf16_bits(v[c] - __bfloat162float(hh));
        } else {
            hb[c] = f16_bits(v[c]);
        }
    }
    reinterpret_cast<ushort4*>(hi)[i] = make_ushort4(hb[0], hb[1], hb[2], hb[3]);
    if (split)
        reinterpret_cast<ushort4*>(lo)[i] = make_ushort4(lb[0], lb[1], lb[2], lb[3]);
}

// ---------------------------------------------------------------------------
// GEMM1 — R7 version, measured 58.4 us (3-pass split-bf16, single acc,
// XOR-swizzled LDS conflicts=0, global_load_lds staging).  UNCHANGED.
// ---------------------------------------------------------------------------
__global__ __launch_bounds__(256) void gemm1_mfma(const unsigned short* __restrict__ Ah,
                                                  const unsigned short* __restrict__ Al,
                                                  const unsigned short* __restrict__ Bh,
                                                  const unsigned short* __restrict__ Bl,
                                                  float* __restrict__ C) {
    __shared__ short AsH[128 * 32];
    __shared__ short AsL[128 * 32];
    __shared__ short BsH[128 * 32];
    __shared__ short BsL[128 * 32];

    const int tid = threadIdx.x;
    const int lane = tid & 63;
    const int wave = tid >> 6;
    const int m0 = blockIdx.x * 128;
    const int n0 = blockIdx.y * 128;
    const int wm = (wave >> 1) * 64;
    const int wn = (wave & 1) * 64;

    const int rsel = lane & 15;
    const int part = lane >> 4;

    int adrA[4], adrB[4];
#pragma unroll
    for (int i = 0; i < 4; i++) {
        const int ra = wm + i * 16 + rsel;
        const int rb = wn + i * 16 + rsel;
        adrA[i] = ra * 32 + (part ^ ((ra >> 1) & 3)) * 8;
        adrB[i] = rb * 32 + (part ^ ((rb >> 1) & 3)) * 8;
    }

    f32x4 acc[4][4] = {};

    for (int k0 = 0; k0 < HH; k0 += 32) {
#pragma unroll
        for (int p = 0; p < 2; p++) {
            const int c = tid + p * 256;
            const int cb = wave * 64 + p * 256;
            const int row = c >> 2;
            const int pslot = c & 3;
            const int pdata = pslot ^ ((row >> 1) & 3);
            const size_t goA = (size_t)(m0 + row) * HH + k0 + pdata * 8;
            const size_t goB = (size_t)(n0 + row) * HH + k0 + pdata * 8;
            GLOAD16(&Ah[goA], &AsH[cb * 8]);
            GLOAD16(&Al[goA], &AsL[cb * 8]);
            GLOAD16(&Bh[goB], &BsH[cb * 8]);
            GLOAD16(&Bl[goB], &BsL[cb * 8]);
        }
        __syncthreads();

        bf16x8 aH[4], aL[4], bH[4], bL[4];
#pragma unroll
        for (int mi = 0; mi < 4; mi++) {
            aH[mi] = *reinterpret_cast<bf16x8*>(&AsH[adrA[mi]]);
            aL[mi] = *reinterpret_cast<bf16x8*>(&AsL[adrA[mi]]);
        }
#pragma unroll
        for (int ni = 0; ni < 4; ni++) {
            bH[ni] = *reinterpret_cast<bf16x8*>(&BsH[adrB[ni]]);
            bL[ni] = *reinterpret_cast<bf16x8*>(&BsL[adrB[ni]]);
        }

#pragma unroll
        for (int mi = 0; mi < 4; mi++)
#pragma unroll
            for (int ni = 0; ni < 4; ni++) {
                acc[mi][ni] = __builtin_amdgcn_mfma_f32_16x16x32_bf16(aH[mi], bH[ni], acc[mi][ni], 0, 0, 0);
                acc[mi][ni] = __builtin_amdgcn_mfma_f32_16x16x32_bf16(aH[mi], bL[ni], acc[mi][ni], 0, 0, 0);
                acc[mi][ni] = __builtin_amdgcn_mfma_f32_16x16x32_bf16(aL[mi], bH[ni], acc[mi][ni], 0, 0, 0);
            }

        __syncthreads();
    }

    const int col = lane & 15;
    const int quad = lane >> 4;
#pragma unroll
    for (int mi = 0; mi < 4; mi++)
#pragma unroll
        for (int ni = 0; ni < 4; ni++) {
            const int m = m0 + wm + mi * 16 + quad * 4;
            const int n = n0 + wn + ni * 16 + col;
            float* dst = &C[(size_t)m * HH + n];
#pragma unroll
            for (int r = 0; r < 4; r++)
                dst[(size_t)r * HH] = acc[mi][ni][r];
        }
}

// ---------------------------------------------------------------------------
// LIF scan — R6 plain version (no prefetch; R7's branchy prefetch reverted).
// ---------------------------------------------------------------------------
__global__ __launch_bounds__(256) void lif_scan_flag(const float* __restrict__ xp,
                                                     unsigned short* __restrict__ sp,
                                                     int* __restrict__ count,
                                                     int* __restrict__ list) {
    const int idx = blockIdx.x * 256 + threadIdx.x;
    double v = 0.0;
    bool flg = false;
#pragma unroll 4
    for (int t = 0; t < TT; t++) {
        const double x = (double)xp[(size_t)t * NLANE + idx];
        const double h = v + (x - v) * 0.5;
        const bool s = (h >= 1.0);
        flg |= (fabs(h - 1.0) < DELTA);
        v = s ? 0.0 : h;
        sp[(size_t)t * NLANE + idx] = s ? (unsigned short)F16_ONE : (unsigned short)0;
    }
    if (flg) {
        const int i = atomicAdd(count, 1);
        list[i] = idx;
    }
}

// ---------------------------------------------------------------------------
// Task-parallel exact f64 dots for flagged lanes (R7 version): one WAVE per
// (li, t) task, coalesced float4 loads, shuffle-reduce.
// ---------------------------------------------------------------------------
__global__ __launch_bounds__(256) void recompute_dots(const float* __restrict__ X,
                                                      const float* __restrict__ W1,
                                                      const int* __restrict__ count,
                                                      const int* __restrict__ list,
                                                      double* __restrict__ hraw) {
    const int cnt = *count;
    const int lim = (cnt < CAPL ? cnt : CAPL);
    const long ntask = (long)lim * TT;
    const int ln = threadIdx.x & 63;
    const long wid = (long)blockIdx.x * 4 + (threadIdx.x >> 6);
    const long nwaves = (long)gridDim.x * 4;

    for (long task = wid; task < ntask; task += nwaves) {
        const int li = (int)(task >> 7);
        const int t = (int)(task & (TT - 1));
        const int lane = list[li];
        const int b = lane >> 10;
        const int h = lane & (HH - 1);
        const float4* x4 = reinterpret_cast<const float4*>(X + (size_t)(t * BB + b) * HH);
        const float4* w4 = reinterpret_cast<const float4*>(W1 + (size_t)h * HH);

        double s0 = 0.0, s1 = 0.0, s2 = 0.0, s3 = 0.0;
#pragma unroll
        for (int i = 0; i < 4; i++) {
            const float4 xa = x4[ln + i * 64];
            const float4 wa = w4[ln + i * 64];
            s0 = fma((double)xa.x, (double)wa.x, s0);
            s1 = fma((double)xa.y, (double)wa.y, s1);
            s2 = fma((double)xa.z, (double)wa.z, s2);
            s3 = fma((double)xa.w, (double)wa.w, s3);
        }
        double s = (s0 + s1) + (s2 + s3);
#pragma unroll
        for (int off = 32; off >= 1; off >>= 1)
            s += __shfl_down(s, off);
        if (ln == 0) hraw[task] = s;
    }
}

// ---------------------------------------------------------------------------
// Exact f64 rescan of flagged lanes from hraw; overwrite their spikes.
// ---------------------------------------------------------------------------
__global__ __launch_bounds__(256) void rescan_lanes(const float* __restrict__ X,
                                                    const float* __restrict__ W1,
                                                    const int* __restrict__ count,
                                                    const int* __restrict__ list,
                                                    const double* __restrict__ hraw,
                                                    unsigned short* __restrict__ sp) {
    const int li = blockIdx.x * 256 + threadIdx.x;
    const int cnt = *count;
    if (li >= cnt) return;
    const int lane = list[li];

    double v = 0.0;
    if (li < CAPL) {
        const double* hb = hraw + (size_t)li * TT;
        for (int t = 0; t < TT; t++) {
            const double h = v + (hb[t] - v) * 0.5;
            const bool s = (h >= 1.0);
            v = s ? 0.0 : h;
            sp[(size_t)t * NLANE + lane] = s ? (unsigned short)F16_ONE : (unsigned short)0;
        }
    } else {
        const int b = lane >> 10;
        const int h = lane & (HH - 1);
        const float* wrow = W1 + (size_t)h * HH;
        for (int t = 0; t < TT; t++) {
            const float* xrow = X + (size_t)(t * BB + b) * HH;
            double d = 0.0;
            for (int k = 0; k < HH; k++)
                d = fma((double)xrow[k], (double)wrow[k], d);
            const double hh = v + (d - v) * 0.5;
            const bool s = (hh >= 1.0);
            v = s ? 0.0 : hh;
            sp[(size_t)t * NLANE + lane] = s ? (unsigned short)F16_ONE : (unsigned short)0;
        }
    }
}

// ---------------------------------------------------------------------------
// GEMM2 — R6 version (BK=32, XOR-swizzled LDS, f16 MFMA; R7's BK=64
// rewrite reverted: it regressed the total by ~20-30 us).
// ---------------------------------------------------------------------------
__global__ __launch_bounds__(256) void gemm2_mfma(const unsigned short* __restrict__ S,
                                                  const unsigned short* __restrict__ W,
                                                  float* __restrict__ O) {
    __shared__ short As[128 * 32];
    __shared__ short Bs[128 * 32];

    const int tid = threadIdx.x;
    const int lane = tid & 63;
    const int wave = tid >> 6;
    const int m0 = blockIdx.x * 128;
    const int n0 = blockIdx.y * 128;
    const int wm = (wave >> 1) * 64;
    const int wn = (wave & 1) * 64;

    const int rsel = lane & 15;
    const int part = lane >> 4;

    int adrA[4], adrB[4];
#pragma unroll
    for (int i = 0; i < 4; i++) {
        const int ra = wm + i * 16 + rsel;
        const int rb = wn + i * 16 + rsel;
        adrA[i] = ra * 32 + (part ^ ((ra >> 1) & 3)) * 8;
        adrB[i] = rb * 32 + (part ^ ((rb >> 1) & 3)) * 8;
    }

    f32x4 acc[4][4] = {};

    for (int k0 = 0; k0 < HH; k0 += 32) {
#pragma unroll
        for (int p = 0; p < 2; p++) {
            const int c = tid + p * 256;
            const int cb = wave * 64 + p * 256;
            const int row = c >> 2;
            const int pslot = c & 3;
            const int pdata = pslot ^ ((row >> 1) & 3);
            GLOAD16(&S[(size_t)(m0 + row) * HH + k0 + pdata * 8], &As[cb * 8]);
            GLOAD16(&W[(size_t)(n0 + row) * HH + k0 + pdata * 8], &Bs[cb * 8]);
        }
        __syncthreads();

        f16x8 a[4], b[4];
#pragma unroll
        for (int mi = 0; mi < 4; mi++)
            a[mi] = *reinterpret_cast<f16x8*>(&As[adrA[mi]]);
#pragma unroll
        for (int ni = 0; ni < 4; ni++)
            b[ni] = *reinterpret_cast<f16x8*>(&Bs[adrB[ni]]);

#pragma unroll
        for (int mi = 0; mi < 4; mi++)
#pragma unroll
            for (int ni = 0; ni < 4; ni++)
                acc[mi][ni] = __builtin_amdgcn_mfma_f32_16x16x32_f16(
                    a[mi], b[ni], acc[mi][ni], 0, 0, 0);

        __syncthreads();
    }

    const int col = lane & 15;
    const int quad = lane >> 4;
#pragma unroll
    for (int mi = 0; mi < 4; mi++)
#pragma unroll
        for (int ni = 0; ni < 4; ni++) {
            const int m = m0 + wm + mi * 16 + quad * 4;
            const int n = n0 + wn + ni * 16 + col;
            float* dst = &O[(size_t)m * HH + n];
#pragma unroll
            for (int r = 0; r < 4; r++)
                dst[(size_t)r * HH] = acc[mi][ni][r];
        }
}

// ---------------------------------------------------------------------------
// Launch (6 dispatches)
// ---------------------------------------------------------------------------
extern "C" void kernel_launch(void* const* d_in, const int* in_sizes, int n_in,
                              void* d_out, int out_size, void* d_ws, size_t ws_size,
                              hipStream_t stream) {
    const float* x  = (const float*)d_in[0];
    const float* W1 = (const float*)d_in[1];
    const float* W2 = (const float*)d_in[2];
    float* out = (float*)d_out;

    char* ws = (char*)d_ws;
    const size_t szX = (size_t)MM * HH;
    const size_t szW = (size_t)HH * HH;

    unsigned short* Xhi  = (unsigned short*)ws;                       // 16.78 MB
    unsigned short* Xlo  = Xhi + szX;                                 // 16.78 MB
    unsigned short* W1hi = Xlo + szX;                                 //  2 MB
    unsigned short* W1lo = W1hi + szW;                                //  2 MB
    unsigned short* w2h  = W1lo + szW;                                //  2 MB
    int*            list = (int*)(w2h + szW);                         // 256 KB
    int*            cnt  = list + NLANE;                              // 4 B
    float*          xp   = (float*)(((uintptr_t)(cnt + 64) + 255) & ~(uintptr_t)255); // 33.5 MB
    unsigned short* sp   = Xhi;          // overlay: spikes reuse Xhi after gemm1
    double*         hraw = (double*)xp;  // overlay: xp dead after lif_scan_flag

    prep_fused<<<10240, 256, 0, stream>>>(x, W1, W2, Xhi, Xlo, W1hi, W1lo, w2h, cnt);

    dim3 g1(MM / 128, HH / 128);
    gemm1_mfma<<<g1, 256, 0, stream>>>(Xhi, Xlo, W1hi, W1lo, xp);

    lif_scan_flag<<<NLANE / 256, 256, 0, stream>>>(xp, sp, cnt, list);

    recompute_dots<<<2048, 256, 0, stream>>>(x, W1, cnt, list, hraw);
    rescan_lanes<<<NLANE / 256, 256, 0, stream>>>(x, W1, cnt, list, hraw, sp);

    dim3 g2(MM / 128, HH / 128);
    gemm2_mfma<<<g2, 256, 0, stream>>>(sp, w2h, out);
}

// Round 9
// 229.867 us; speedup vs baseline: 1.0818x; 1.0173x over previous
//
#include <hip/hip_runtime.h>
#include <hip/hip_bf16.h>
#include <stdint.h>

// Problem constants (T=128, B=64, H=1024)
#define TT 128
#define BB 64
#define HH 1024
#define MM (TT * BB)          // 8192 rows of the two GEMMs
#define NLANE (BB * HH)       // 65536 scan lanes
#define DELTA 1.0e-4          // flag band; bf16 3-pass worst-tail ~6e-5 (1.7x margin,
                              // held R7+R8) — do NOT shrink
#define CAPL 32768            // hraw capacity in lanes (overlay on xp region)
#define F16_ONE 0x3C00        // _Float16 1.0

typedef __attribute__((ext_vector_type(8))) short bf16x8;
typedef __attribute__((ext_vector_type(8))) _Float16 f16x8;
typedef __attribute__((ext_vector_type(4))) float f32x4;

// async global->LDS, 16 B per lane; LDS dest = wave-uniform base + lane*16
#define GLOAD16(g, l)                                                        \
    __builtin_amdgcn_global_load_lds(                                        \
        (const __attribute__((address_space(1))) unsigned int*)(g),          \
        (__attribute__((address_space(3))) unsigned int*)(l), 16, 0, 0)

static __device__ __forceinline__ unsigned short bf16_bits(float f) {
    __hip_bfloat16 b = __float2bfloat16(f);
    return *reinterpret_cast<unsigned short*>(&b);
}
static __device__ __forceinline__ unsigned short f16_bits(float f) {
    _Float16 h = (_Float16)f;
    return *reinterpret_cast<unsigned short*>(&h);
}

// ---------------------------------------------------------------------------
// Fused prep (one dispatch) — R6/R8 version, unchanged.
// ---------------------------------------------------------------------------
__global__ __launch_bounds__(256) void prep_fused(const float* __restrict__ x,
                                                  const float* __restrict__ W1,
                                                  const float* __restrict__ W2,
                                                  unsigned short* __restrict__ Xhi,
                                                  unsigned short* __restrict__ Xlo,
                                                  unsigned short* __restrict__ W1hi,
                                                  unsigned short* __restrict__ W1lo,
                                                  unsigned short* __restrict__ w2h,
                                                  int* __restrict__ cnt) {
    const int bid = blockIdx.x;
    if (bid == 0 && threadIdx.x == 0) *cnt = 0;

    const float* src;
    unsigned short *hi, *lo;
    int i;
    bool split;
    if (bid < 8192) {
        i = bid * 256 + threadIdx.x;
        src = x; hi = Xhi; lo = Xlo; split = true;
    } else if (bid < 9216) {
        i = (bid - 8192) * 256 + threadIdx.x;
        src = W1; hi = W1hi; lo = W1lo; split = true;
    } else {
        i = (bid - 9216) * 256 + threadIdx.x;
        src = W2; hi = w2h; lo = nullptr; split = false;
    }

    float4 v4 = reinterpret_cast<const float4*>(src)[i];
    float v[4] = {v4.x, v4.y, v4.z, v4.w};
    unsigned short hb[4], lb[4];
#pragma unroll
    for (int c = 0; c < 4; c++) {
        if (split) {
            hb[c] = bf16_bits(v[c]);
            __hip_bfloat16 hh = *reinterpret_cast<__hip_bfloat16*>(&hb[c]);
            lb[c] = bf16_bits(v[c] - __bfloat162float(hh));
        } else {
            hb[c] = f16_bits(v[c]);
        }
    }
    reinterpret_cast<ushort4*>(hi)[i] = make_ushort4(hb[0], hb[1], hb[2], hb[3]);
    if (split)
        reinterpret_cast<ushort4*>(lo)[i] = make_ushort4(lb[0], lb[1], lb[2], lb[3]);
}

// ---------------------------------------------------------------------------
// GEMM1 — measured 58.4-59.7 us across R7/R8 (3-pass split-bf16, single acc,
// XOR-swizzled LDS conflicts=0, global_load_lds).  BYTE-IDENTICAL to R8.
// ---------------------------------------------------------------------------
__global__ __launch_bounds__(256) void gemm1_mfma(const unsigned short* __restrict__ Ah,
                                                  const unsigned short* __restrict__ Al,
                                                  const unsigned short* __restrict__ Bh,
                                                  const unsigned short* __restrict__ Bl,
                                                  float* __restrict__ C) {
    __shared__ short AsH[128 * 32];
    __shared__ short AsL[128 * 32];
    __shared__ short BsH[128 * 32];
    __shared__ short BsL[128 * 32];

    const int tid = threadIdx.x;
    const int lane = tid & 63;
    const int wave = tid >> 6;
    const int m0 = blockIdx.x * 128;
    const int n0 = blockIdx.y * 128;
    const int wm = (wave >> 1) * 64;
    const int wn = (wave & 1) * 64;

    const int rsel = lane & 15;
    const int part = lane >> 4;

    int adrA[4], adrB[4];
#pragma unroll
    for (int i = 0; i < 4; i++) {
        const int ra = wm + i * 16 + rsel;
        const int rb = wn + i * 16 + rsel;
        adrA[i] = ra * 32 + (part ^ ((ra >> 1) & 3)) * 8;
        adrB[i] = rb * 32 + (part ^ ((rb >> 1) & 3)) * 8;
    }

    f32x4 acc[4][4] = {};

    for (int k0 = 0; k0 < HH; k0 += 32) {
#pragma unroll
        for (int p = 0; p < 2; p++) {
            const int c = tid + p * 256;
            const int cb = wave * 64 + p * 256;
            const int row = c >> 2;
            const int pslot = c & 3;
            const int pdata = pslot ^ ((row >> 1) & 3);
            const size_t goA = (size_t)(m0 + row) * HH + k0 + pdata * 8;
            const size_t goB = (size_t)(n0 + row) * HH + k0 + pdata * 8;
            GLOAD16(&Ah[goA], &AsH[cb * 8]);
            GLOAD16(&Al[goA], &AsL[cb * 8]);
            GLOAD16(&Bh[goB], &BsH[cb * 8]);
            GLOAD16(&Bl[goB], &BsL[cb * 8]);
        }
        __syncthreads();

        bf16x8 aH[4], aL[4], bH[4], bL[4];
#pragma unroll
        for (int mi = 0; mi < 4; mi++) {
            aH[mi] = *reinterpret_cast<bf16x8*>(&AsH[adrA[mi]]);
            aL[mi] = *reinterpret_cast<bf16x8*>(&AsL[adrA[mi]]);
        }
#pragma unroll
        for (int ni = 0; ni < 4; ni++) {
            bH[ni] = *reinterpret_cast<bf16x8*>(&BsH[adrB[ni]]);
            bL[ni] = *reinterpret_cast<bf16x8*>(&BsL[adrB[ni]]);
        }

#pragma unroll
        for (int mi = 0; mi < 4; mi++)
#pragma unroll
            for (int ni = 0; ni < 4; ni++) {
                acc[mi][ni] = __builtin_amdgcn_mfma_f32_16x16x32_bf16(aH[mi], bH[ni], acc[mi][ni], 0, 0, 0);
                acc[mi][ni] = __builtin_amdgcn_mfma_f32_16x16x32_bf16(aH[mi], bL[ni], acc[mi][ni], 0, 0, 0);
                acc[mi][ni] = __builtin_amdgcn_mfma_f32_16x16x32_bf16(aL[mi], bH[ni], acc[mi][ni], 0, 0, 0);
            }

        __syncthreads();
    }

    const int col = lane & 15;
    const int quad = lane >> 4;
#pragma unroll
    for (int mi = 0; mi < 4; mi++)
#pragma unroll
        for (int ni = 0; ni < 4; ni++) {
            const int m = m0 + wm + mi * 16 + quad * 4;
            const int n = n0 + wn + ni * 16 + col;
            float* dst = &C[(size_t)m * HH + n];
#pragma unroll
            for (int r = 0; r < 4; r++)
                dst[(size_t)r * HH] = acc[mi][ni][r];
        }
}

// ---------------------------------------------------------------------------
// LIF scan — R6/R8 plain version, unchanged.
// ---------------------------------------------------------------------------
__global__ __launch_bounds__(256) void lif_scan_flag(const float* __restrict__ xp,
                                                     unsigned short* __restrict__ sp,
                                                     int* __restrict__ count,
                                                     int* __restrict__ list) {
    const int idx = blockIdx.x * 256 + threadIdx.x;
    double v = 0.0;
    bool flg = false;
#pragma unroll 4
    for (int t = 0; t < TT; t++) {
        const double x = (double)xp[(size_t)t * NLANE + idx];
        const double h = v + (x - v) * 0.5;
        const bool s = (h >= 1.0);
        flg |= (fabs(h - 1.0) < DELTA);
        v = s ? 0.0 : h;
        sp[(size_t)t * NLANE + idx] = s ? (unsigned short)F16_ONE : (unsigned short)0;
    }
    if (flg) {
        const int i = atomicAdd(count, 1);
        list[i] = idx;
    }
}

// ---------------------------------------------------------------------------
// Task-parallel exact f64 dots for flagged lanes — R7/R8 version, unchanged.
// ---------------------------------------------------------------------------
__global__ __launch_bounds__(256) void recompute_dots(const float* __restrict__ X,
                                                      const float* __restrict__ W1,
                                                      const int* __restrict__ count,
                                                      const int* __restrict__ list,
                                                      double* __restrict__ hraw) {
    const int cnt = *count;
    const int lim = (cnt < CAPL ? cnt : CAPL);
    const long ntask = (long)lim * TT;
    const int ln = threadIdx.x & 63;
    const long wid = (long)blockIdx.x * 4 + (threadIdx.x >> 6);
    const long nwaves = (long)gridDim.x * 4;

    for (long task = wid; task < ntask; task += nwaves) {
        const int li = (int)(task >> 7);
        const int t = (int)(task & (TT - 1));
        const int lane = list[li];
        const int b = lane >> 10;
        const int h = lane & (HH - 1);
        const float4* x4 = reinterpret_cast<const float4*>(X + (size_t)(t * BB + b) * HH);
        const float4* w4 = reinterpret_cast<const float4*>(W1 + (size_t)h * HH);

        double s0 = 0.0, s1 = 0.0, s2 = 0.0, s3 = 0.0;
#pragma unroll
        for (int i = 0; i < 4; i++) {
            const float4 xa = x4[ln + i * 64];
            const float4 wa = w4[ln + i * 64];
            s0 = fma((double)xa.x, (double)wa.x, s0);
            s1 = fma((double)xa.y, (double)wa.y, s1);
            s2 = fma((double)xa.z, (double)wa.z, s2);
            s3 = fma((double)xa.w, (double)wa.w, s3);
        }
        double s = (s0 + s1) + (s2 + s3);
#pragma unroll
        for (int off = 32; off >= 1; off >>= 1)
            s += __shfl_down(s, off);
        if (ln == 0) hraw[task] = s;
    }
}

// ---------------------------------------------------------------------------
// Exact f64 rescan of flagged lanes — R7/R8 version, unchanged.
// ---------------------------------------------------------------------------
__global__ __launch_bounds__(256) void rescan_lanes(const float* __restrict__ X,
                                                    const float* __restrict__ W1,
                                                    const int* __restrict__ count,
                                                    const int* __restrict__ list,
                                                    const double* __restrict__ hraw,
                                                    unsigned short* __restrict__ sp) {
    const int li = blockIdx.x * 256 + threadIdx.x;
    const int cnt = *count;
    if (li >= cnt) return;
    const int lane = list[li];

    double v = 0.0;
    if (li < CAPL) {
        const double* hb = hraw + (size_t)li * TT;
        for (int t = 0; t < TT; t++) {
            const double h = v + (hb[t] - v) * 0.5;
            const bool s = (h >= 1.0);
            v = s ? 0.0 : h;
            sp[(size_t)t * NLANE + lane] = s ? (unsigned short)F16_ONE : (unsigned short)0;
        }
    } else {
        const int b = lane >> 10;
        const int h = lane & (HH - 1);
        const float* wrow = W1 + (size_t)h * HH;
        for (int t = 0; t < TT; t++) {
            const float* xrow = X + (size_t)(t * BB + b) * HH;
            double d = 0.0;
            for (int k = 0; k < HH; k++)
                d = fma((double)xrow[k], (double)wrow[k], d);
            const double hh = v + (d - v) * 0.5;
            const bool s = (hh >= 1.0);
            v = s ? 0.0 : hh;
            sp[(size_t)t * NLANE + lane] = s ? (unsigned short)F16_ONE : (unsigned short)0;
        }
    }
}

// ---------------------------------------------------------------------------
// GEMM2 — ROUND-9 CHANGE: 128x64 tile (was 128x128).
// grid (64,16) = 1024 blocks = 4 blocks/CU (was 2): doubles cross-block
// barrier overlap (m114 mechanism) and halves acc regs (32 f32/thread).
// 4 waves in 2(M)x2(N): wave tile 64x32, frags 4x2.  BK=32, XOR swizzle,
// global_load_lds staging (A: 512 chunks, B: 256 chunks, 3/thread).
// ---------------------------------------------------------------------------
__global__ __launch_bounds__(256) void gemm2_mfma(const unsigned short* __restrict__ S,
                                                  const unsigned short* __restrict__ W,
                                                  float* __restrict__ O) {
    __shared__ short As[128 * 32];   // 8 KB
    __shared__ short Bs[64 * 32];    // 4 KB

    const int tid = threadIdx.x;
    const int lane = tid & 63;
    const int wave = tid >> 6;
    const int m0 = blockIdx.x * 128;   // 64 blocks in M
    const int n0 = blockIdx.y * 64;    // 16 blocks in N
    const int wm = (wave >> 1) * 64;   // {0,64}
    const int wn = (wave & 1) * 32;    // {0,32}

    const int rsel = lane & 15;
    const int part = lane >> 4;

    int adrA[4], adrB[2];
#pragma unroll
    for (int i = 0; i < 4; i++) {
        const int ra = wm + i * 16 + rsel;
        adrA[i] = ra * 32 + (part ^ ((ra >> 1) & 3)) * 8;
    }
#pragma unroll
    for (int i = 0; i < 2; i++) {
        const int rb = wn + i * 16 + rsel;
        adrB[i] = rb * 32 + (part ^ ((rb >> 1) & 3)) * 8;
    }

    f32x4 acc[4][2] = {};

    for (int k0 = 0; k0 < HH; k0 += 32) {
        // 768 chunks: A = 0..511, B = 512..767; wave-uniform sides (64 | 256)
#pragma unroll
        for (int p = 0; p < 3; p++) {
            const int c = tid + p * 256;
            const int cb = wave * 64 + p * 256;
            if (c < 512) {
                const int row = c >> 2;
                const int pslot = c & 3;
                const int pdata = pslot ^ ((row >> 1) & 3);
                GLOAD16(&S[(size_t)(m0 + row) * HH + k0 + pdata * 8], &As[cb * 8]);
            } else {
                const int c2 = c - 512;
                const int row = c2 >> 2;
                const int pslot = c2 & 3;
                const int pdata = pslot ^ ((row >> 1) & 3);
                GLOAD16(&W[(size_t)(n0 + row) * HH + k0 + pdata * 8], &Bs[(cb - 512) * 8]);
            }
        }
        __syncthreads();

        f16x8 a[4], b[2];
#pragma unroll
        for (int mi = 0; mi < 4; mi++)
            a[mi] = *reinterpret_cast<f16x8*>(&As[adrA[mi]]);
#pragma unroll
        for (int ni = 0; ni < 2; ni++)
            b[ni] = *reinterpret_cast<f16x8*>(&Bs[adrB[ni]]);

#pragma unroll
        for (int mi = 0; mi < 4; mi++)
#pragma unroll
            for (int ni = 0; ni < 2; ni++)
                acc[mi][ni] = __builtin_amdgcn_mfma_f32_16x16x32_f16(
                    a[mi], b[ni], acc[mi][ni], 0, 0, 0);

        __syncthreads();
    }

    const int col = lane & 15;
    const int quad = lane >> 4;
#pragma unroll
    for (int mi = 0; mi < 4; mi++)
#pragma unroll
        for (int ni = 0; ni < 2; ni++) {
            const int m = m0 + wm + mi * 16 + quad * 4;
            const int n = n0 + wn + ni * 16 + col;
            float* dst = &O[(size_t)m * HH + n];
#pragma unroll
            for (int r = 0; r < 4; r++)
                dst[(size_t)r * HH] = acc[mi][ni][r];
        }
}

// ---------------------------------------------------------------------------
// Launch (6 dispatches)
// ---------------------------------------------------------------------------
extern "C" void kernel_launch(void* const* d_in, const int* in_sizes, int n_in,
                              void* d_out, int out_size, void* d_ws, size_t ws_size,
                              hipStream_t stream) {
    const float* x  = (const float*)d_in[0];
    const float* W1 = (const float*)d_in[1];
    const float* W2 = (const float*)d_in[2];
    float* out = (float*)d_out;

    char* ws = (char*)d_ws;
    const size_t szX = (size_t)MM * HH;
    const size_t szW = (size_t)HH * HH;

    unsigned short* Xhi  = (unsigned short*)ws;                       // 16.78 MB
    unsigned short* Xlo  = Xhi + szX;                                 // 16.78 MB
    unsigned short* W1hi = Xlo + szX;                                 //  2 MB
    unsigned short* W1lo = W1hi + szW;                                //  2 MB
    unsigned short* w2h  = W1lo + szW;                                //  2 MB
    int*            list = (int*)(w2h + szW);                         // 256 KB
    int*            cnt  = list + NLANE;                              // 4 B
    float*          xp   = (float*)(((uintptr_t)(cnt + 64) + 255) & ~(uintptr_t)255); // 33.5 MB
    unsigned short* sp   = Xhi;          // overlay: spikes reuse Xhi after gemm1
    double*         hraw = (double*)xp;  // overlay: xp dead after lif_scan_flag

    prep_fused<<<10240, 256, 0, stream>>>(x, W1, W2, Xhi, Xlo, W1hi, W1lo, w2h, cnt);

    dim3 g1(MM / 128, HH / 128);
    gemm1_mfma<<<g1, 256, 0, stream>>>(Xhi, Xlo, W1hi, W1lo, xp);

    lif_scan_flag<<<NLANE / 256, 256, 0, stream>>>(xp, sp, cnt, list);

    recompute_dots<<<2048, 256, 0, stream>>>(x, W1, cnt, list, hraw);
    rescan_lanes<<<NLANE / 256, 256, 0, stream>>>(x, W1, cnt, list, hraw, sp);

    dim3 g2(MM / 128, HH / 64);
    gemm2_mfma<<<g2, 256, 0, stream>>>(sp, w2h, out);
}

// Round 10
// 217.670 us; speedup vs baseline: 1.1424x; 1.0560x over previous
//
#include <hip/hip_runtime.h>
#include <hip/hip_bf16.h>
#include <stdint.h>

// Problem constants (T=128, B=64, H=1024)
#define TT 128
#define BB 64
#define HH 1024
#define MM (TT * BB)          // 8192 rows of the two GEMMs
#define NLANE (BB * HH)       // 65536 scan lanes
#define DELTA 1.0e-4          // flag band; bf16 3-pass worst-tail ~6e-5 (1.7x margin,
                              // held R7-R9) — do NOT shrink
#define F16_ONE 0x3C00        // _Float16 1.0

typedef __attribute__((ext_vector_type(8))) short bf16x8;
typedef __attribute__((ext_vector_type(8))) _Float16 f16x8;
typedef __attribute__((ext_vector_type(4))) float f32x4;

// async global->LDS, 16 B per lane; LDS dest = wave-uniform base + lane*16
#define GLOAD16(g, l)                                                        \
    __builtin_amdgcn_global_load_lds(                                        \
        (const __attribute__((address_space(1))) unsigned int*)(g),          \
        (__attribute__((address_space(3))) unsigned int*)(l), 16, 0, 0)

static __device__ __forceinline__ unsigned short bf16_bits(float f) {
    __hip_bfloat16 b = __float2bfloat16(f);
    return *reinterpret_cast<unsigned short*>(&b);
}
static __device__ __forceinline__ unsigned short f16_bits(float f) {
    _Float16 h = (_Float16)f;
    return *reinterpret_cast<unsigned short*>(&h);
}

// ---------------------------------------------------------------------------
// Fused prep (one dispatch) — R6/R8/R9 version, unchanged.
// ---------------------------------------------------------------------------
__global__ __launch_bounds__(256) void prep_fused(const float* __restrict__ x,
                                                  const float* __restrict__ W1,
                                                  const float* __restrict__ W2,
                                                  unsigned short* __restrict__ Xhi,
                                                  unsigned short* __restrict__ Xlo,
                                                  unsigned short* __restrict__ W1hi,
                                                  unsigned short* __restrict__ W1lo,
                                                  unsigned short* __restrict__ w2h,
                                                  int* __restrict__ cnt) {
    const int bid = blockIdx.x;
    if (bid == 0 && threadIdx.x == 0) *cnt = 0;

    const float* src;
    unsigned short *hi, *lo;
    int i;
    bool split;
    if (bid < 8192) {
        i = bid * 256 + threadIdx.x;
        src = x; hi = Xhi; lo = Xlo; split = true;
    } else if (bid < 9216) {
        i = (bid - 8192) * 256 + threadIdx.x;
        src = W1; hi = W1hi; lo = W1lo; split = true;
    } else {
        i = (bid - 9216) * 256 + threadIdx.x;
        src = W2; hi = w2h; lo = nullptr; split = false;
    }

    float4 v4 = reinterpret_cast<const float4*>(src)[i];
    float v[4] = {v4.x, v4.y, v4.z, v4.w};
    unsigned short hb[4], lb[4];
#pragma unroll
    for (int c = 0; c < 4; c++) {
        if (split) {
            hb[c] = bf16_bits(v[c]);
            __hip_bfloat16 hh = *reinterpret_cast<__hip_bfloat16*>(&hb[c]);
            lb[c] = bf16_bits(v[c] - __bfloat162float(hh));
        } else {
            hb[c] = f16_bits(v[c]);
        }
    }
    reinterpret_cast<ushort4*>(hi)[i] = make_ushort4(hb[0], hb[1], hb[2], hb[3]);
    if (split)
        reinterpret_cast<ushort4*>(lo)[i] = make_ushort4(lb[0], lb[1], lb[2], lb[3]);
}

// ---------------------------------------------------------------------------
// GEMM1 — measured 58.4-61.2 us across R7-R9 (3-pass split-bf16, single acc,
// XOR-swizzled LDS conflicts=0, global_load_lds).  BYTE-IDENTICAL to R8/R9.
// ---------------------------------------------------------------------------
__global__ __launch_bounds__(256) void gemm1_mfma(const unsigned short* __restrict__ Ah,
                                                  const unsigned short* __restrict__ Al,
                                                  const unsigned short* __restrict__ Bh,
                                                  const unsigned short* __restrict__ Bl,
                                                  float* __restrict__ C) {
    __shared__ short AsH[128 * 32];
    __shared__ short AsL[128 * 32];
    __shared__ short BsH[128 * 32];
    __shared__ short BsL[128 * 32];

    const int tid = threadIdx.x;
    const int lane = tid & 63;
    const int wave = tid >> 6;
    const int m0 = blockIdx.x * 128;
    const int n0 = blockIdx.y * 128;
    const int wm = (wave >> 1) * 64;
    const int wn = (wave & 1) * 64;

    const int rsel = lane & 15;
    const int part = lane >> 4;

    int adrA[4], adrB[4];
#pragma unroll
    for (int i = 0; i < 4; i++) {
        const int ra = wm + i * 16 + rsel;
        const int rb = wn + i * 16 + rsel;
        adrA[i] = ra * 32 + (part ^ ((ra >> 1) & 3)) * 8;
        adrB[i] = rb * 32 + (part ^ ((rb >> 1) & 3)) * 8;
    }

    f32x4 acc[4][4] = {};

    for (int k0 = 0; k0 < HH; k0 += 32) {
#pragma unroll
        for (int p = 0; p < 2; p++) {
            const int c = tid + p * 256;
            const int cb = wave * 64 + p * 256;
            const int row = c >> 2;
            const int pslot = c & 3;
            const int pdata = pslot ^ ((row >> 1) & 3);
            const size_t goA = (size_t)(m0 + row) * HH + k0 + pdata * 8;
            const size_t goB = (size_t)(n0 + row) * HH + k0 + pdata * 8;
            GLOAD16(&Ah[goA], &AsH[cb * 8]);
            GLOAD16(&Al[goA], &AsL[cb * 8]);
            GLOAD16(&Bh[goB], &BsH[cb * 8]);
            GLOAD16(&Bl[goB], &BsL[cb * 8]);
        }
        __syncthreads();

        bf16x8 aH[4], aL[4], bH[4], bL[4];
#pragma unroll
        for (int mi = 0; mi < 4; mi++) {
            aH[mi] = *reinterpret_cast<bf16x8*>(&AsH[adrA[mi]]);
            aL[mi] = *reinterpret_cast<bf16x8*>(&AsL[adrA[mi]]);
        }
#pragma unroll
        for (int ni = 0; ni < 4; ni++) {
            bH[ni] = *reinterpret_cast<bf16x8*>(&BsH[adrB[ni]]);
            bL[ni] = *reinterpret_cast<bf16x8*>(&BsL[adrB[ni]]);
        }

#pragma unroll
        for (int mi = 0; mi < 4; mi++)
#pragma unroll
            for (int ni = 0; ni < 4; ni++) {
                acc[mi][ni] = __builtin_amdgcn_mfma_f32_16x16x32_bf16(aH[mi], bH[ni], acc[mi][ni], 0, 0, 0);
                acc[mi][ni] = __builtin_amdgcn_mfma_f32_16x16x32_bf16(aH[mi], bL[ni], acc[mi][ni], 0, 0, 0);
                acc[mi][ni] = __builtin_amdgcn_mfma_f32_16x16x32_bf16(aL[mi], bH[ni], acc[mi][ni], 0, 0, 0);
            }

        __syncthreads();
    }

    const int col = lane & 15;
    const int quad = lane >> 4;
#pragma unroll
    for (int mi = 0; mi < 4; mi++)
#pragma unroll
        for (int ni = 0; ni < 4; ni++) {
            const int m = m0 + wm + mi * 16 + quad * 4;
            const int n = n0 + wn + ni * 16 + col;
            float* dst = &C[(size_t)m * HH + n];
#pragma unroll
            for (int r = 0; r < 4; r++)
                dst[(size_t)r * HH] = acc[mi][ni][r];
        }
}

// ---------------------------------------------------------------------------
// LIF scan — R6/R8/R9 plain version, unchanged.
// ---------------------------------------------------------------------------
__global__ __launch_bounds__(256) void lif_scan_flag(const float* __restrict__ xp,
                                                     unsigned short* __restrict__ sp,
                                                     int* __restrict__ count,
                                                     int* __restrict__ list) {
    const int idx = blockIdx.x * 256 + threadIdx.x;
    double v = 0.0;
    bool flg = false;
#pragma unroll 4
    for (int t = 0; t < TT; t++) {
        const double x = (double)xp[(size_t)t * NLANE + idx];
        const double h = v + (x - v) * 0.5;
        const bool s = (h >= 1.0);
        flg |= (fabs(h - 1.0) < DELTA);
        v = s ? 0.0 : h;
        sp[(size_t)t * NLANE + idx] = s ? (unsigned short)F16_ONE : (unsigned short)0;
    }
    if (flg) {
        const int i = atomicAdd(count, 1);
        list[i] = idx;
    }
}

// ---------------------------------------------------------------------------
// ROUND-10 CHANGE: fused exact-recompute, ONE dispatch (replaces R9's
// dots+rescan pair whose rescan was ~20 us of serial global-latency).
// Block (1024 thr = 16 waves) <- flagged lane, grid-stride over cnt.
// Wave w computes t = w, w+16, ... (8 sequential f64 dots, float4-coalesced,
// shuffle-reduced) -> LDS hbuf[128]; thread 0 then runs the exact f64 scan
// from LDS (~120cyc/read vs ~400cyc global in R9's rescan) and overwrites
// the lane's spikes.  Correct for any cnt.
// ---------------------------------------------------------------------------
__global__ __launch_bounds__(1024) void recompute_fused(const float* __restrict__ X,
                                                        const float* __restrict__ W1,
                                                        const int* __restrict__ count,
                                                        const int* __restrict__ list,
                                                        unsigned short* __restrict__ sp) {
    __shared__ double hbuf[TT];
    const int cnt = *count;
    const int wv = threadIdx.x >> 6;   // 0..15
    const int ln = threadIdx.x & 63;

    for (int li = blockIdx.x; li < cnt; li += gridDim.x) {
        const int lane = list[li];
        const int b = lane >> 10;
        const int h = lane & (HH - 1);
        const float4* w4 = reinterpret_cast<const float4*>(W1 + (size_t)h * HH);

        for (int t = wv; t < TT; t += 16) {
            const float4* x4 = reinterpret_cast<const float4*>(X + (size_t)(t * BB + b) * HH);
            double s0 = 0.0, s1 = 0.0, s2 = 0.0, s3 = 0.0;
#pragma unroll
            for (int i = 0; i < 4; i++) {
                const float4 xa = x4[ln + i * 64];
                const float4 wa = w4[ln + i * 64];
                s0 = fma((double)xa.x, (double)wa.x, s0);
                s1 = fma((double)xa.y, (double)wa.y, s1);
                s2 = fma((double)xa.z, (double)wa.z, s2);
                s3 = fma((double)xa.w, (double)wa.w, s3);
            }
            double s = (s0 + s1) + (s2 + s3);
#pragma unroll
            for (int off = 32; off >= 1; off >>= 1)
                s += __shfl_down(s, off);
            if (ln == 0) hbuf[t] = s;
        }
        __syncthreads();

        if (threadIdx.x == 0) {
            double v = 0.0;
            for (int t = 0; t < TT; t++) {
                const double hh = v + (hbuf[t] - v) * 0.5;
                const bool s = (hh >= 1.0);
                v = s ? 0.0 : hh;
                sp[(size_t)t * NLANE + lane] = s ? (unsigned short)F16_ONE : (unsigned short)0;
            }
        }
        __syncthreads();
    }
}

// ---------------------------------------------------------------------------
// GEMM2 — 128x64 tile (R9, kept) with ROUND-10 grid transpose: blockIdx.x
// now indexes N so each run of 16 consecutive blocks shares one 256 KB S
// m-tile (L2-local re-read instead of L3).
// ---------------------------------------------------------------------------
__global__ __launch_bounds__(256) void gemm2_mfma(const unsigned short* __restrict__ S,
                                                  const unsigned short* __restrict__ W,
                                                  float* __restrict__ O) {
    __shared__ short As[128 * 32];   // 8 KB
    __shared__ short Bs[64 * 32];    // 4 KB

    const int tid = threadIdx.x;
    const int lane = tid & 63;
    const int wave = tid >> 6;
    const int m0 = blockIdx.y * 128;   // 64 blocks in M (slow axis)
    const int n0 = blockIdx.x * 64;    // 16 blocks in N (fast axis)
    const int wm = (wave >> 1) * 64;   // {0,64}
    const int wn = (wave & 1) * 32;    // {0,32}

    const int rsel = lane & 15;
    const int part = lane >> 4;

    int adrA[4], adrB[2];
#pragma unroll
    for (int i = 0; i < 4; i++) {
        const int ra = wm + i * 16 + rsel;
        adrA[i] = ra * 32 + (part ^ ((ra >> 1) & 3)) * 8;
    }
#pragma unroll
    for (int i = 0; i < 2; i++) {
        const int rb = wn + i * 16 + rsel;
        adrB[i] = rb * 32 + (part ^ ((rb >> 1) & 3)) * 8;
    }

    f32x4 acc[4][2] = {};

    for (int k0 = 0; k0 < HH; k0 += 32) {
        // 768 chunks: A = 0..511, B = 512..767; wave-uniform sides (64 | 256)
#pragma unroll
        for (int p = 0; p < 3; p++) {
            const int c = tid + p * 256;
            const int cb = wave * 64 + p * 256;
            if (c < 512) {
                const int row = c >> 2;
                const int pslot = c & 3;
                const int pdata = pslot ^ ((row >> 1) & 3);
                GLOAD16(&S[(size_t)(m0 + row) * HH + k0 + pdata * 8], &As[cb * 8]);
            } else {
                const int c2 = c - 512;
                const int row = c2 >> 2;
                const int pslot = c2 & 3;
                const int pdata = pslot ^ ((row >> 1) & 3);
                GLOAD16(&W[(size_t)(n0 + row) * HH + k0 + pdata * 8], &Bs[(cb - 512) * 8]);
            }
        }
        __syncthreads();

        f16x8 a[4], b[2];
#pragma unroll
        for (int mi = 0; mi < 4; mi++)
            a[mi] = *reinterpret_cast<f16x8*>(&As[adrA[mi]]);
#pragma unroll
        for (int ni = 0; ni < 2; ni++)
            b[ni] = *reinterpret_cast<f16x8*>(&Bs[adrB[ni]]);

#pragma unroll
        for (int mi = 0; mi < 4; mi++)
#pragma unroll
            for (int ni = 0; ni < 2; ni++)
                acc[mi][ni] = __builtin_amdgcn_mfma_f32_16x16x32_f16(
                    a[mi], b[ni], acc[mi][ni], 0, 0, 0);

        __syncthreads();
    }

    const int col = lane & 15;
    const int quad = lane >> 4;
#pragma unroll
    for (int mi = 0; mi < 4; mi++)
#pragma unroll
        for (int ni = 0; ni < 2; ni++) {
            const int m = m0 + wm + mi * 16 + quad * 4;
            const int n = n0 + wn + ni * 16 + col;
            float* dst = &O[(size_t)m * HH + n];
#pragma unroll
            for (int r = 0; r < 4; r++)
                dst[(size_t)r * HH] = acc[mi][ni][r];
        }
}

// ---------------------------------------------------------------------------
// Launch (5 dispatches)
// ---------------------------------------------------------------------------
extern "C" void kernel_launch(void* const* d_in, const int* in_sizes, int n_in,
                              void* d_out, int out_size, void* d_ws, size_t ws_size,
                              hipStream_t stream) {
    const float* x  = (const float*)d_in[0];
    const float* W1 = (const float*)d_in[1];
    const float* W2 = (const float*)d_in[2];
    float* out = (float*)d_out;

    char* ws = (char*)d_ws;
    const size_t szX = (size_t)MM * HH;
    const size_t szW = (size_t)HH * HH;

    unsigned short* Xhi  = (unsigned short*)ws;                       // 16.78 MB
    unsigned short* Xlo  = Xhi + szX;                                 // 16.78 MB
    unsigned short* W1hi = Xlo + szX;                                 //  2 MB
    unsigned short* W1lo = W1hi + szW;                                //  2 MB
    unsigned short* w2h  = W1lo + szW;                                //  2 MB
    int*            list = (int*)(w2h + szW);                         // 256 KB
    int*            cnt  = list + NLANE;                              // 4 B
    float*          xp   = (float*)(((uintptr_t)(cnt + 64) + 255) & ~(uintptr_t)255); // 33.5 MB
    unsigned short* sp   = Xhi;          // overlay: spikes reuse Xhi after gemm1

    prep_fused<<<10240, 256, 0, stream>>>(x, W1, W2, Xhi, Xlo, W1hi, W1lo, w2h, cnt);

    dim3 g1(MM / 128, HH / 128);
    gemm1_mfma<<<g1, 256, 0, stream>>>(Xhi, Xlo, W1hi, W1lo, xp);

    lif_scan_flag<<<NLANE / 256, 256, 0, stream>>>(xp, sp, cnt, list);

    recompute_fused<<<512, 1024, 0, stream>>>(x, W1, cnt, list, sp);

    dim3 g2(HH / 64, MM / 128);   // x = N (fast): 16 consecutive blocks share an S m-tile
    gemm2_mfma<<<g2, 256, 0, stream>>>(sp, w2h, out);
}